// Round 2
// baseline (101.276 us; speedup 1.0000x reference)
//
#include <hip/hip_runtime.h>
#include <math.h>

// Problem constants: B=2, C=16, D=64, H=128, W=128, K=4
#define SPATIAL (64 * 128 * 128)   // 2^20 voxels per sample
#define NCLS 16
#define NB 2
#define NBLK 2048                  // 2048 blocks * 256 thr * 4 vox = 2*SPATIAL exactly
#define TPB 256

// Fused single kernel: stream probs/target once (17 loads in flight per thread),
// block-reduce 5 scalars, last-arriving block (ticket) does the final reduction.
__global__ __launch_bounds__(TPB) void bce_fused(
    const float* __restrict__ probs,     // [B, C, SPATIAL]
    const int*   __restrict__ target,    // [B, SPATIAL]
    const int*   __restrict__ ann,       // [B, 4]
    float*       __restrict__ partials,  // [5][NBLK] in d_ws
    unsigned*    __restrict__ counter,   // 1 uint in d_ws (zeroed by memsetAsync)
    float*       __restrict__ out)       // out[0]=ce, out[1]=reg
{
    const int j = blockIdx.x * TPB + threadIdx.x;  // work item: 4 consecutive voxels
    const int v = j * 4;
    const int b = v >> 20;                         // sample (SPATIAL = 2^20); wave-uniform
    const int s = v & (SPATIAL - 1);

    // Issue ALL global loads up front: 1x int4 + 16x float4 in flight per thread.
    const int4 t4 = *reinterpret_cast<const int4*>(target + v);
    const float* pb = probs + (size_t)b * NCLS * SPATIAL + s;
    float4 p4[NCLS];
#pragma unroll
    for (int c = 0; c < NCLS; ++c)
        p4[c] = *reinterpret_cast<const float4*>(pb + (size_t)c * SPATIAL);

    // Unannotated-class bitmask for this sample (scalar loads, wave-uniform).
    unsigned a = 0;
#pragma unroll
    for (int k = 0; k < 4; ++k) {
        const int c = ann[b * 4 + k];
        if (c > 0) a |= (1u << c);
    }
    const unsigned m = ~a & 0xFFFFu;

    const int t[4] = {t4.x, t4.y, t4.z, t4.w};
    float ent[4] = {0.f, 0.f, 0.f, 0.f};  // sum_c p*log2(clamp(p))
    float s0[4]  = {0.f, 0.f, 0.f, 0.f};  // sum of unannotated-class probs
    float pt[4]  = {0.f, 0.f, 0.f, 0.f};  // prob at target class

#pragma unroll
    for (int c = 0; c < NCLS; ++c) {
        const float p[4] = {p4[c].x, p4[c].y, p4[c].z, p4[c].w};
        const bool un = (m >> c) & 1u;
#pragma unroll
        for (int q = 0; q < 4; ++q) {
            const float pc = fminf(fmaxf(p[q], 1e-6f), 0.999999f);
            ent[q] = fmaf(p[q], __log2f(pc), ent[q]);
            if (un) s0[q] += p[q];
            if (c == t[q]) pt[q] = p[q];
        }
    }

    float ce_sum = 0.f, ent_b = 0.f, cnt_b = 0.f;
#pragma unroll
    for (int q = 0; q < 4; ++q) {
        const float p  = (t[q] > 0) ? pt[q] : s0[q];
        const float pc = fminf(fmaxf(p, 1e-6f), 0.999999f);
        const float om = 1.f - p;                   // focal term uses UNclamped p
        ce_sum += om * om * __log2f(pc);
        ent_b  += ent[q];
        cnt_b  += (t[q] != 0) ? 1.f : 0.f;
    }

    float vals[5];
    vals[0] = ce_sum;
    vals[1] = (b == 0) ? ent_b : 0.f;
    vals[2] = (b == 1) ? ent_b : 0.f;
    vals[3] = (b == 0) ? cnt_b : 0.f;
    vals[4] = (b == 1) ? cnt_b : 0.f;

    // Block reduction: shuffle tree within wave, LDS across waves.
    __shared__ float red[5][TPB / 64];
    __shared__ int   lastFlag;
    const int lane = threadIdx.x & 63;
    const int wave = threadIdx.x >> 6;
#pragma unroll
    for (int qq = 0; qq < 5; ++qq) {
        float x = vals[qq];
#pragma unroll
        for (int off = 32; off > 0; off >>= 1)
            x += __shfl_down(x, off, 64);
        if (lane == 0) red[qq][wave] = x;
    }
    __syncthreads();
    if (threadIdx.x == 0) {
#pragma unroll
        for (int qq = 0; qq < 5; ++qq) {
            float x = 0.f;
#pragma unroll
            for (int w = 0; w < TPB / 64; ++w) x += red[qq][w];
            // agent-scope store so other XCDs' last block sees it
            __hip_atomic_store(&partials[qq * NBLK + blockIdx.x], x,
                               __ATOMIC_RELAXED, __HIP_MEMORY_SCOPE_AGENT);
        }
        __threadfence();                              // release partials
        const unsigned old = atomicAdd(counter, 1u);  // device-scope ticket
        lastFlag = (old == NBLK - 1) ? 1 : 0;
    }
    __syncthreads();
    if (!lastFlag) return;

    // ---- last block: deterministic tree-sum of all block partials ----
    __threadfence();  // acquire
    float acc[5] = {0.f, 0.f, 0.f, 0.f, 0.f};
    for (int i = threadIdx.x; i < NBLK; i += TPB) {
#pragma unroll
        for (int qq = 0; qq < 5; ++qq)
            acc[qq] += __hip_atomic_load(&partials[qq * NBLK + i],
                                         __ATOMIC_RELAXED, __HIP_MEMORY_SCOPE_AGENT);
    }
    __syncthreads();  // red[] reuse
#pragma unroll
    for (int qq = 0; qq < 5; ++qq) {
        float x = acc[qq];
#pragma unroll
        for (int off = 32; off > 0; off >>= 1)
            x += __shfl_down(x, off, 64);
        if (lane == 0) red[qq][wave] = x;
    }
    __syncthreads();
    if (threadIdx.x == 0) {
        float ce = 0.f, e0 = 0.f, e1 = 0.f, c0 = 0.f, c1 = 0.f;
#pragma unroll
        for (int w = 0; w < TPB / 64; ++w) {
            ce += red[0][w]; e0 += red[1][w]; e1 += red[2][w];
            c0 += red[3][w]; c1 += red[4][w];
        }
        const float LN2  = 0.69314718055994530942f;
        const float invS = 1.f / (float)SPATIAL;
        const float ent0 = e0 * LN2 * invS;
        const float ent1 = e1 * LN2 * invS;
        const float m0   = (c0 == 0.f) ? 3.f : 1.f;   // all_bg -> MULT_UNLABELED
        const float m1   = (c1 == 0.f) ? 3.f : 1.f;
        out[0] = -(ce * LN2) / (float)(NB * SPATIAL); // balanced focal CE
        out[1] = -(m0 * ent0 + m1 * ent1) * 0.5f;     // regularization
    }
}

extern "C" void kernel_launch(void* const* d_in, const int* in_sizes, int n_in,
                              void* d_out, int out_size, void* d_ws, size_t ws_size,
                              hipStream_t stream) {
    const float* probs  = (const float*)d_in[0];
    const int*   target = (const int*)d_in[1];
    const int*   ann    = (const int*)d_in[2];
    float*       out    = (float*)d_out;

    float*    partials = (float*)d_ws;                         // 5*NBLK*4 = 40 KiB
    unsigned* counter  = (unsigned*)((char*)d_ws + 5 * NBLK * sizeof(float));

    hipMemsetAsync(counter, 0, sizeof(unsigned), stream);      // graph-safe ticket reset
    bce_fused<<<NBLK, TPB, 0, stream>>>(probs, target, ann, partials, counter, out);
}

// Round 3
// 36.920 us; speedup vs baseline: 2.7432x; 2.7432x over previous
//
#include <hip/hip_runtime.h>
#include <math.h>

// Problem constants: B=2, C=16, D=64, H=128, W=128, K=4
#define SPATIAL (64 * 128 * 128)   // 2^20 voxels per sample
#define NCLS 16
#define NB 2
#define NBLK 2048                  // 2048 blocks * 256 thr * 4 vox = 2*SPATIAL exactly
#define TPB 256

// ---------------- main pass: stream probs/target once, 4 voxels/thread ----------------
// Chunked double-buffered prefetch: 4 classes (4x float4) ahead -> ~8 loads in
// flight, ~64-80 VGPR live (NO 16-wide array: R2 showed that spills to scratch).
__global__ __launch_bounds__(TPB) void bce_main(
    const float* __restrict__ probs,    // [B, C, SPATIAL]
    const int*   __restrict__ target,   // [B, SPATIAL]
    const int*   __restrict__ ann,      // [B, 4]
    float*       __restrict__ partials) // [5][NBLK]: ce, ent_b0, ent_b1, cnt_b0, cnt_b1
{
    const int j = blockIdx.x * TPB + threadIdx.x;
    const int v = j * 4;                 // first voxel
    const int b = v >> 20;               // sample (SPATIAL = 2^20); wave-uniform
    const int s = v & (SPATIAL - 1);

    const int4 t4 = *reinterpret_cast<const int4*>(target + v);
    const int t[4] = {t4.x, t4.y, t4.z, t4.w};

    // Unannotated-class bitmask (class 0 never annotated as fg); wave-uniform.
    unsigned a = 0;
#pragma unroll
    for (int k = 0; k < 4; ++k) {
        const int c = ann[b * 4 + k];
        if (c > 0) a |= (1u << c);
    }
    const unsigned m = ~a & 0xFFFFu;

    const float* pb = probs + (size_t)b * NCLS * SPATIAL + s;

    float ent[4] = {0.f, 0.f, 0.f, 0.f};
    float s0[4]  = {0.f, 0.f, 0.f, 0.f};
    float pt[4]  = {0.f, 0.f, 0.f, 0.f};

    // Pipeline: buf[2][4], chunk = 4 classes. All indices compile-time constant.
    float4 buf[2][4];
#pragma unroll
    for (int c = 0; c < 4; ++c)
        buf[0][c] = *reinterpret_cast<const float4*>(pb + (size_t)c * SPATIAL);

#pragma unroll
    for (int ch = 0; ch < 4; ++ch) {
        const int cur = ch & 1, nxt = cur ^ 1;
        if (ch < 3) {
#pragma unroll
            for (int c = 0; c < 4; ++c)
                buf[nxt][c] = *reinterpret_cast<const float4*>(
                    pb + (size_t)((ch + 1) * 4 + c) * SPATIAL);
        }
#pragma unroll
        for (int c = 0; c < 4; ++c) {
            const int cls = ch * 4 + c;
            const float p[4] = {buf[cur][c].x, buf[cur][c].y, buf[cur][c].z, buf[cur][c].w};
            const bool un = (m >> cls) & 1u;
#pragma unroll
            for (int q = 0; q < 4; ++q) {
                const float pc = fminf(fmaxf(p[q], 1e-6f), 0.999999f);
                ent[q] = fmaf(p[q], __log2f(pc), ent[q]);
                if (un) s0[q] += p[q];
                if (cls == t[q]) pt[q] = p[q];
            }
        }
    }

    float ce_sum = 0.f, ent_b = 0.f, cnt_b = 0.f;
#pragma unroll
    for (int q = 0; q < 4; ++q) {
        const float p  = (t[q] > 0) ? pt[q] : s0[q];
        const float pc = fminf(fmaxf(p, 1e-6f), 0.999999f);
        const float om = 1.f - p;                   // focal uses UNclamped p
        ce_sum += om * om * __log2f(pc);
        ent_b  += ent[q];
        cnt_b  += (t[q] != 0) ? 1.f : 0.f;
    }

    float vals[5];
    vals[0] = ce_sum;
    vals[1] = (b == 0) ? ent_b : 0.f;
    vals[2] = (b == 1) ? ent_b : 0.f;
    vals[3] = (b == 0) ? cnt_b : 0.f;
    vals[4] = (b == 1) ? cnt_b : 0.f;

    __shared__ float red[5][TPB / 64];
    const int lane = threadIdx.x & 63;
    const int wave = threadIdx.x >> 6;
#pragma unroll
    for (int qq = 0; qq < 5; ++qq) {
        float x = vals[qq];
#pragma unroll
        for (int off = 32; off > 0; off >>= 1)
            x += __shfl_down(x, off, 64);
        if (lane == 0) red[qq][wave] = x;
    }
    __syncthreads();
    if (threadIdx.x == 0) {
#pragma unroll
        for (int qq = 0; qq < 5; ++qq) {
            float x = 0.f;
#pragma unroll
            for (int w = 0; w < TPB / 64; ++w) x += red[qq][w];
            partials[qq * NBLK + blockIdx.x] = x;
        }
    }
}

// ---------------- finalize: single wave, no barriers, float4 reads ----------------
__global__ __launch_bounds__(64) void bce_final(
    const float* __restrict__ partials, float* __restrict__ out)
{
    const int lane = threadIdx.x;   // 64 threads = 1 wave
    // Each quantity stream: 2048 floats = 64 lanes * 8 float4.
    float acc[5] = {0.f, 0.f, 0.f, 0.f, 0.f};
#pragma unroll
    for (int qq = 0; qq < 5; ++qq) {
        const float4* src = reinterpret_cast<const float4*>(partials + qq * NBLK);
#pragma unroll
        for (int i = 0; i < 8; ++i) {
            const float4 x = src[i * 64 + lane];
            acc[qq] += (x.x + x.y) + (x.z + x.w);
        }
    }
#pragma unroll
    for (int qq = 0; qq < 5; ++qq) {
#pragma unroll
        for (int off = 32; off > 0; off >>= 1)
            acc[qq] += __shfl_down(acc[qq], off, 64);
    }
    if (lane == 0) {
        const float ce = acc[0], e0 = acc[1], e1 = acc[2], c0 = acc[3], c1 = acc[4];
        const float LN2  = 0.69314718055994530942f;
        const float invS = 1.f / (float)SPATIAL;
        const float ent0 = e0 * LN2 * invS;
        const float ent1 = e1 * LN2 * invS;
        const float m0   = (c0 == 0.f) ? 3.f : 1.f;   // all_bg -> MULT_UNLABELED
        const float m1   = (c1 == 0.f) ? 3.f : 1.f;
        out[0] = -(ce * LN2) / (float)(NB * SPATIAL);
        out[1] = -(m0 * ent0 + m1 * ent1) * 0.5f;
    }
}

extern "C" void kernel_launch(void* const* d_in, const int* in_sizes, int n_in,
                              void* d_out, int out_size, void* d_ws, size_t ws_size,
                              hipStream_t stream) {
    const float* probs  = (const float*)d_in[0];
    const int*   target = (const int*)d_in[1];
    const int*   ann    = (const int*)d_in[2];
    float*       out    = (float*)d_out;
    float*       partials = (float*)d_ws;   // 5 * NBLK * 4 B = 40 KiB

    bce_main<<<NBLK, TPB, 0, stream>>>(probs, target, ann, partials);
    bce_final<<<1, 64, 0, stream>>>(partials, out);
}